// Round 11
// baseline (209.952 us; speedup 1.0000x reference)
//
#include <hip/hip_runtime.h>

// Causal single-head attention, B=4 S=4096 Dm=256 Dqk=64, fp32 in/out.
// R19 = R15 (best: attn 40.4us, total 202.8, VGPR 72) + anti-convoy pass.
// Falsified: specialization(R9), TLP(R11 +4%), atomics(R14), addr-VALU(R16),
// S^T chain(R17), barrier count(R18). Model: phase convoy — all 8 waves do
// S^T/exp (VALU/trans) then PV (matrix) in lockstep; the 2 co-resident blocks
// drift into phase-alignment and pipes serialize (sum-of-phases 5.5k cyc/cell
// vs max-of-phases ~1.7k; SIMD issue ~50%). Changes (all bitwise-identical
// math):
//  (1) s_setprio(1) around S^T and PV, (0) around exp/pack: the block in its
//      MFMA phase outranks the co-resident block in its VALU phase -> creates
//      the anti-phase overlap the scheduler won't find alone (T5; m191 attn
//      +4-7% in exactly this independent-group regime).
//  (2) per-quad exp/mask/pack: kills pv[16] live range (-8-12 VGPR), same
//      FP order (r = 4*quad+i ascending, pd chain order preserved).
//  (3) PV reads P in batches of 8 ds_read_b128 (pa0[4]/pa1[4] per half-pass)
//      ahead of 4 MFMA pairs -> deeper LDS pipelining; same kc/qsl order.
// Structure frozen at R15: 480 blocks x 512 thr, 2 blocks/CU, XCD slot pin,
// Pb double-buffer, 1 barrier/iter, V use-then-refill, K prefetch across
// barrier. proj/combine/ws unchanged.
// ws: qf 2MB + kf 2MB + vf 8MB + Op 7.34MB + Dp 98KB = 19.5MB.

#define BATCH 4
#define SEQ   4096
#define DM    256
#define DQK   64

typedef __bf16 bf16x8 __attribute__((ext_vector_type(8)));
typedef __bf16 bf16x2 __attribute__((ext_vector_type(2)));
typedef float  f32x16 __attribute__((ext_vector_type(16)));

// HW RNE float->bf16 (v_cvt_pk_bf16_f32 via compiler).
__device__ __forceinline__ unsigned short f2bf(float f) {
    __bf16 h = (__bf16)f;
    return __builtin_bit_cast(unsigned short, h);
}
__device__ __forceinline__ unsigned int pk2bf(float lo, float hi) {
    bf16x2 v = {(__bf16)lo, (__bf16)hi};    // elem0 low, elem1 high
    return __builtin_bit_cast(unsigned int, v);
}
__device__ __forceinline__ bf16x8 u4bf(uint4 u) { return __builtin_bit_cast(bf16x8, u); }

// Repack a 32x32x16 MFMA accumulator D[m][n] (C-layout: col(n)=lane&31,
// row(m)=(r&3)+8(r>>2)+4(lane>>5)) into two 1KB fragment chunks where the
// fragment k-dim = m and lane-dim = n, then store. (Verified R2/R3.)
__device__ __forceinline__ void repack_store(const f32x16& acc, int q2, int l,
                                             uint4* __restrict__ out, size_t tile_ofs_u4) {
    unsigned int d0[4], d1[4], p0[4], p1[4];
#pragma unroll
    for (int h = 0; h < 4; ++h) {
        d0[h] = pk2bf(acc[4*h + 0], acc[4*h + 1]);
        d1[h] = pk2bf(acc[4*h + 2], acc[4*h + 3]);
        p0[h] = __shfl_xor((int)d0[h], 32);
        p1[h] = __shfl_xor((int)d1[h], 32);
    }
#pragma unroll
    for (int kc = 0; kc < 2; ++kc) {
        int h = 2*kc + q2;
        uint4 v = (q2 == 0) ? make_uint4(d0[h], d1[h], p0[h], p1[h])
                            : make_uint4(p0[h], p1[h], d0[h], d1[h]);
        out[tile_ofs_u4 + (size_t)kc * 64 + l] = v;
    }
}

// R3 task map: nc=1 (T<12), 2 (12..23), 3 (24..31).
// Op slots (chunks cc>=1): T 12..23 -> 1 slot, 24..31 -> 2. 28/batch.
__device__ __forceinline__ int obase(int T) {
    return (T < 24) ? (T - 12) : 12 + (T - 24) * 2;
}
// Dp slots (all chunks of split tasks): 48/batch.
__device__ __forceinline__ int dbase(int T) {
    return (T < 24) ? (T - 12) * 2 : 24 + (T - 24) * 3;
}

// ---------------------------------------------------------------------------
// Fused projection. grid (64 s-tiles, 4 batch, 3): z=0 Q, z=1 K, z=2 V (all
// 4 e-chunks; Xv staged once).  (Unchanged from R12.)
// ---------------------------------------------------------------------------
__global__ __launch_bounds__(256) void proj(const float* __restrict__ Xq,
                                            const float* __restrict__ Xk,
                                            const float* __restrict__ Xv,
                                            const float* __restrict__ Wq,
                                            const float* __restrict__ Wk,
                                            const float* __restrict__ Wv,
                                            uint4* __restrict__ qf,
                                            uint4* __restrict__ kf,
                                            uint4* __restrict__ vf) {
    __shared__ unsigned short Xs[64][264];
    __shared__ unsigned short Ws[64][264];

    const int z = blockIdx.z;
    const int bx = blockIdx.x, b = blockIdx.y;
    const float* X = (z == 0) ? Xq : (z == 1) ? Xk : Xv;
    const float* W = (z == 0) ? Wq : (z == 1) ? Wk : Wv;
    const int s0 = bx * 64;
    const int tid = threadIdx.x, w = tid >> 6, l = tid & 63, ln = l & 31, q2 = l >> 5;

#pragma unroll
    for (int i = 0; i < 16; ++i) {
        int f = i * 256 + tid;
        int r = f >> 6, c4 = f & 63;
        float4 xv = *(const float4*)&X[((size_t)b * SEQ + s0 + r) * DM + c4 * 4];
        ushort4 h; h.x = f2bf(xv.x); h.y = f2bf(xv.y); h.z = f2bf(xv.z); h.w = f2bf(xv.w);
        *(ushort4*)&Xs[r][c4 * 4] = h;
    }

    if (z < 2) {
#pragma unroll
        for (int i = 0; i < 16; ++i) {
            int f = i * 256 + tid;
            int r = f >> 6, c4 = f & 63;
            float4 wv = *(const float4*)&W[(size_t)r * DM + c4 * 4];
            ushort4 h; h.x = f2bf(wv.x); h.y = f2bf(wv.y); h.z = f2bf(wv.z); h.w = f2bf(wv.w);
            *(ushort4*)&Ws[r][c4 * 4] = h;
        }
        __syncthreads();
        const int msub = w >> 1, nsub = w & 1;
        f32x16 a0 = {}, a1 = {};
#pragma unroll
        for (int c = 0; c < 16; c += 2) {
            bf16x8 af0 = u4bf(*(const uint4*)&Ws[msub*32 + ln][c*16 + q2*8]);
            bf16x8 bf0 = u4bf(*(const uint4*)&Xs[nsub*32 + ln][c*16 + q2*8]);
            a0 = __builtin_amdgcn_mfma_f32_32x32x16_bf16(af0, bf0, a0, 0, 0, 0);
            bf16x8 af1 = u4bf(*(const uint4*)&Ws[msub*32 + ln][(c+1)*16 + q2*8]);
            bf16x8 bf1 = u4bf(*(const uint4*)&Xs[nsub*32 + ln][(c+1)*16 + q2*8]);
            a1 = __builtin_amdgcn_mfma_f32_32x32x16_bf16(af1, bf1, a1, 0, 0, 0);
        }
        f32x16 acc = a0 + a1;
        size_t base = (((size_t)(b*128 + bx*2 + nsub)) * 4 + 2*msub) * 64;
        repack_store(acc, q2, l, (z == 0) ? qf : kf, base);
    } else {
        const int msub = w & 1, nsub = w >> 1;
        for (int ec = 0; ec < 4; ++ec) {
            __syncthreads();
#pragma unroll
            for (int i = 0; i < 16; ++i) {
                int f = i * 256 + tid;
                int r = f >> 6, c4 = f & 63;
                float4 wv = *(const float4*)&W[(size_t)(ec*64 + r) * DM + c4 * 4];
                ushort4 h; h.x = f2bf(wv.x); h.y = f2bf(wv.y); h.z = f2bf(wv.z); h.w = f2bf(wv.w);
                *(ushort4*)&Ws[r][c4 * 4] = h;
            }
            __syncthreads();
            f32x16 a0 = {}, a1 = {};
#pragma unroll
            for (int c = 0; c < 16; c += 2) {
                bf16x8 af0 = u4bf(*(const uint4*)&Xs[msub*32 + ln][c*16 + q2*8]);
                bf16x8 bf0 = u4bf(*(const uint4*)&Ws[nsub*32 + ln][c*16 + q2*8]);
                a0 = __builtin_amdgcn_mfma_f32_32x32x16_bf16(af0, bf0, a0, 0, 0, 0);
                bf16x8 af1 = u4bf(*(const uint4*)&Xs[msub*32 + ln][(c+1)*16 + q2*8]);
                bf16x8 bf1 = u4bf(*(const uint4*)&Ws[nsub*32 + ln][(c+1)*16 + q2*8]);
                a1 = __builtin_amdgcn_mfma_f32_32x32x16_bf16(af1, bf1, a1, 0, 0, 0);
            }
            f32x16 acc = a0 + a1;
            int et = ec*2 + nsub;
            size_t base = (((size_t)(b*8 + et)) * 256 + (size_t)bx*4 + msub*2) * 64;
            repack_store(acc, q2, l, vf, base);
        }
    }
}

// ---------------------------------------------------------------------------
// Attention. 480 blocks x 512 thr, 2 blocks/CU. slot = bid&7 -> b, qh (XCD
// pin). task = bid>>3 -> (T, cc of nc), chunk [j0,j1). Wave w: S^T (ks=w&3,
// qg=w>>2), PV (et=w). R19: setprio phase-marking, per-quad exp/pack,
// batched P reads. Math bitwise = R15.
// ---------------------------------------------------------------------------
__global__ __launch_bounds__(512, 2) void attn(const uint4* __restrict__ qf,
                                               const uint4* __restrict__ kf,
                                               const uint4* __restrict__ vf,
                                               float* __restrict__ out,
                                               unsigned short* __restrict__ Op,
                                               float* __restrict__ Dp) {
    __shared__ uint4 Pb[2][2][8][64];        // 32KB, double-buffered P (64 rows)
    __shared__ float denp[4][2][64];         // [ks][qg][lane]
    __shared__ float dfin[64];

    const int bid = blockIdx.x;
    const int slot = bid & 7;
    const int b = slot >> 1, qh = slot & 1;
    const int task = bid >> 3;               // [0,60)
    int T, cc, nc;
    if (task < 12)      { T = task;                cc = 0;               nc = 1; }
    else if (task < 36) { int q = task - 12; T = 12 + (q >> 1); cc = q & 1;       nc = 2; }
    else                { int q = task - 36; T = 24 + q / 3;    cc = q - 3*(q/3); nc = 3; }
    const int n = T + 1;
    const int j0 = cc * n / nc, j1 = (cc + 1) * n / nc;

    const int tid = threadIdx.x, w = tid >> 6, l = tid & 63, ln = l & 31, q2 = l >> 5;
    const int ks = w & 3, qg = w >> 2;       // S^T role
    const int qsub = qh * 2 + qg;            // global q-sub within T-tile
    const int et = w;                        // PV role: e-tile
    const float cfac = 0.18033688011112042f; // log2(e)/sqrt(64)

    bf16x8 qv[4];
#pragma unroll
    for (int c = 0; c < 4; ++c)
        qv[c] = u4bf(qf[(((size_t)b*128 + T*4 + qsub) * 4 + c) * 64 + l]);

    f32x16 oa[2] = {};
    float den = 0.f;

    uint4 kaf[4];
#pragma unroll
    for (int c = 0; c < 4; ++c)
        kaf[c] = kf[(((size_t)b*128 + j0*4 + ks) * 4 + c) * 64 + l];

    // initial V fill for tile j0 (latency covered by first S^T/exp)
    const size_t vbase = ((size_t)b*8 + et) * 256;
    uint4 vbs[8];
#pragma unroll
    for (int kc = 0; kc < 8; ++kc)
        vbs[kc] = vf[(vbase + (size_t)j0*8 + kc) * 64 + l];

    for (int jt = j0; jt < j1; ++jt) {
        const int buf = jt & 1;
        const bool diag = (jt == T);
        const int jn = (jt + 1 < j1) ? jt + 1 : jt;  // clamped next tile

        // ---- S^T (MFMA phase: prio 1) ----
        __builtin_amdgcn_s_setprio(1);
        f32x16 s = {};
#pragma unroll
        for (int c = 0; c < 4; ++c)
            s = __builtin_amdgcn_mfma_f32_32x32x16_bf16(u4bf(kaf[c]), qv[c], s, 0, 0, 0);
        __builtin_amdgcn_s_setprio(0);

        // ---- exp + mask + den + pack, per-quad (VALU phase: prio 0) ----
        float pd = 0.f;
#pragma unroll
        for (int quad = 0; quad < 4; ++quad) {
            float ev[4];
#pragma unroll
            for (int i = 0; i < 4; ++i) {
                float e = __builtin_exp2f(s[4*quad + i] * cfac);
                if (diag) {
                    int klocal = 4*q2 + i + 8*quad;
                    if (ks*32 + klocal > qsub*32 + ln) e = 0.f;
                }
                ev[i] = e; pd += e;
            }
            unsigned int lo = pk2bf(ev[0], ev[1]);
            unsigned int hi = pk2bf(ev[2], ev[3]);
            int kcg = ks*2 + (quad >> 1);
            int h   = quad & 1;
            char* dst = (char*)&Pb[buf][qg][kcg][h*32 + ln] + q2*8;
            *(uint2*)dst = make_uint2(lo, hi);
        }
        den += pd;
        __syncthreads();
        // ---- prefetch next K-frags (covered by PV) ----
        if (jt + 1 < j1) {
#pragma unroll
            for (int c = 0; c < 4; ++c)
                kaf[c] = kf[(((size_t)b*128 + (jt+1)*4 + ks) * 4 + c) * 64 + l];
        }
        // ---- PV (MFMA phase: prio 1), batched P reads per half-pass ----
        __builtin_amdgcn_s_setprio(1);
#pragma unroll
        for (int kh = 0; kh < 2; ++kh) {
            bf16x8 pa0[4], pa1[4];
#pragma unroll
            for (int i = 0; i < 4; ++i) {
                pa0[i] = u4bf(Pb[buf][0][kh*4 + i][l]);
                pa1[i] = u4bf(Pb[buf][1][kh*4 + i][l]);
            }
#pragma unroll
            for (int i = 0; i < 4; ++i) {
                const int kc = kh*4 + i;
                bf16x8 vb = u4bf(vbs[kc]);
                vbs[kc] = vf[(vbase + (size_t)jn*8 + kc) * 64 + l];
                oa[0] = __builtin_amdgcn_mfma_f32_32x32x16_bf16(pa0[i], vb, oa[0], 0, 0, 0);
                oa[1] = __builtin_amdgcn_mfma_f32_32x32x16_bf16(pa1[i], vb, oa[1], 0, 0, 0);
            }
        }
        __builtin_amdgcn_s_setprio(0);
    }

    // ---- den reduction across ks-waves/halves (order matches R15 bitwise) ----
    denp[ks][qg][l] = den;
    __syncthreads();
    if (tid < 64) {
        int qgl = tid >> 5, qln = tid & 31;
        float sden = 0.f;
#pragma unroll
        for (int p = 0; p < 4; ++p)
#pragma unroll
            for (int hh = 0; hh < 2; ++hh)
                sden += denp[p][qgl][hh*32 + qln];
        dfin[tid] = (nc == 1) ? 1.0f / sden : sden;
    }
    __syncthreads();

    if (nc == 1) {
#pragma unroll
        for (int qsl = 0; qsl < 2; ++qsl)
#pragma unroll
            for (int r = 0; r < 16; ++r) {
                int qrow = qsl*32 + (r & 3) + 8*(r >> 2) + 4*q2;
                out[((size_t)b*SEQ + T*128 + qh*64 + qrow) * DM + et*32 + ln] = oa[qsl][r] * dfin[qrow];
            }
    } else if (cc == 0) {
        // chunk 0: unnormalized fp32 straight into out (combine divides later)
#pragma unroll
        for (int qsl = 0; qsl < 2; ++qsl)
#pragma unroll
            for (int r = 0; r < 16; ++r) {
                int qrow = qsl*32 + (r & 3) + 8*(r >> 2) + 4*q2;
                out[((size_t)b*SEQ + T*128 + qh*64 + qrow) * DM + et*32 + ln] = oa[qsl][r];
            }
        if (tid < 64) Dp[((size_t)b*48 + dbase(T)) * 128 + qh*64 + tid] = dfin[tid];
    } else {
        size_t pidx = (size_t)b*28 + obase(T) + (cc - 1);
#pragma unroll
        for (int qsl = 0; qsl < 2; ++qsl)
#pragma unroll
            for (int r = 0; r < 16; ++r) {
                int qrow = qsl*32 + (r & 3) + 8*(r >> 2) + 4*q2;
                Op[(pidx*128 + qh*64 + qrow) * DM + et*32 + ln] = f2bf(oa[qsl][r]);
            }
        if (tid < 64) Dp[((size_t)b*48 + dbase(T) + cc) * 128 + qh*64 + tid] = dfin[tid];
    }
}

// ---------------------------------------------------------------------------
// Combine partials for T in [12,32). grid (20, 4, 4 q-quarters) x 256 thr.
// out holds chunk-0's unnormalized fp32; add bf16 chunks >=1, divide by den.
// (Unchanged.)
// ---------------------------------------------------------------------------
__global__ __launch_bounds__(256) void combine(const unsigned short* __restrict__ Op,
                                               const float* __restrict__ Dp,
                                               float* __restrict__ out) {
    const int T = 12 + blockIdx.x, b = blockIdx.y, qq = blockIdx.z;
    const int nc = (T < 24) ? 2 : 3;
    const int t = threadIdx.x;
    const size_t db = (size_t)b*48 + dbase(T);
    const size_t pb = (size_t)b*28 + obase(T);
#pragma unroll 4
    for (int r = 0; r < 32; ++r) {
        int q = qq*32 + r;
        size_t oofs = ((size_t)b*SEQ + T*128 + q) * DM + t;
        float sum = out[oofs];
        float dsum = 0.f;
        for (int c = 0; c < nc; ++c) dsum += Dp[(db + c)*128 + q];
        for (int c = 1; c < nc; ++c) {
            unsigned int uv = Op[((pb + c - 1)*128 + q) * DM + t];
            sum += __builtin_bit_cast(float, uv << 16);
        }
        out[oofs] = sum / dsum;
    }
}

// ---------------------------------------------------------------------------
extern "C" void kernel_launch(void* const* d_in, const int* in_sizes, int n_in,
                              void* d_out, int out_size, void* d_ws, size_t ws_size,
                              hipStream_t stream) {
    const float* enc_q = (const float*)d_in[0];
    const float* enc_k = (const float*)d_in[1];
    const float* enc_v = (const float*)d_in[2];
    // d_in[3] = mask (deterministic causal triu) — not needed
    const float* Wq = (const float*)d_in[4];
    const float* Wk = (const float*)d_in[5];
    const float* Wv = (const float*)d_in[6];
    float* out = (float*)d_out;

    uint4* qf = (uint4*)d_ws;                              // 2MB
    uint4* kf = qf + 131072;                               // 2MB
    uint4* vf = kf + 131072;                               // 8MB
    unsigned short* Op = (unsigned short*)(vf + 524288);   // [4][28][128][256] bf16, 7.34MB
    float* Dp = (float*)(Op + (size_t)4*28*128*256);       // [4][48][128] f32, 98KB

    proj<<<dim3(64, 4, 3), 256, 0, stream>>>(enc_q, enc_k, enc_v, Wq, Wk, Wv, qf, kf, vf);
    attn<<<480, 512, 0, stream>>>(qf, kf, vf, out, Op, Dp);
    combine<<<dim3(20, 4, 4), 256, 0, stream>>>(Op, Dp, out);
}

// Round 12
// 203.842 us; speedup vs baseline: 1.0300x; 1.0300x over previous
//
#include <hip/hip_runtime.h>

// Causal single-head attention, B=4 S=4096 Dm=256 Dqk=64, fp32 in/out.
// R20 = R15 verbatim (champion: attn 40.4us, total 202.8, VGPR 72).
// R19 (setprio phase-marking + per-quad pack + batched P reads) REGRESSED
// 40.4->48.4 — setprio on this lockstep structure penalizes the co-resident
// block (guide m190 GEMM-lockstep null applies, not m191). Final ledger:
// R9 specialization ✗(spill) | R11 TLP ✓(+4%) | R12 HW-cvt ✓(-7us) |
// R14 atomics ✗ | R15 V-refill ✓(-5.6us) | R16 addr-VALU ✗ | R17 S^T chain ✗
// | R18 barrier count ✗ | R19 setprio ✗. All HIP-source-level levers tested.
// R15 recap: 480 blocks x 512 thr, 2 blocks/CU, XCD slot pin (slot=bid&7 ->
// b,qh), task chunking (nc=1/2/3), Pb double-buffer, 1 barrier/iter, V
// use-then-refill (vbs[kc] reloaded for jt+1 right after last PV use), K
// prefetched across the barrier. HW bf16 cvt (R12). Op/Dp/combine partials.
// ws: qf 2MB + kf 2MB + vf 8MB + Op 7.34MB + Dp 98KB = 19.5MB.

#define BATCH 4
#define SEQ   4096
#define DM    256
#define DQK   64

typedef __bf16 bf16x8 __attribute__((ext_vector_type(8)));
typedef __bf16 bf16x2 __attribute__((ext_vector_type(2)));
typedef float  f32x16 __attribute__((ext_vector_type(16)));

// HW RNE float->bf16 (v_cvt_pk_bf16_f32 via compiler).
__device__ __forceinline__ unsigned short f2bf(float f) {
    __bf16 h = (__bf16)f;
    return __builtin_bit_cast(unsigned short, h);
}
__device__ __forceinline__ unsigned int pk2bf(float lo, float hi) {
    bf16x2 v = {(__bf16)lo, (__bf16)hi};    // elem0 low, elem1 high
    return __builtin_bit_cast(unsigned int, v);
}
__device__ __forceinline__ bf16x8 u4bf(uint4 u) { return __builtin_bit_cast(bf16x8, u); }

// Repack a 32x32x16 MFMA accumulator D[m][n] (C-layout: col(n)=lane&31,
// row(m)=(r&3)+8(r>>2)+4(lane>>5)) into two 1KB fragment chunks where the
// fragment k-dim = m and lane-dim = n, then store. (Verified R2/R3.)
__device__ __forceinline__ void repack_store(const f32x16& acc, int q2, int l,
                                             uint4* __restrict__ out, size_t tile_ofs_u4) {
    unsigned int d0[4], d1[4], p0[4], p1[4];
#pragma unroll
    for (int h = 0; h < 4; ++h) {
        d0[h] = pk2bf(acc[4*h + 0], acc[4*h + 1]);
        d1[h] = pk2bf(acc[4*h + 2], acc[4*h + 3]);
        p0[h] = __shfl_xor((int)d0[h], 32);
        p1[h] = __shfl_xor((int)d1[h], 32);
    }
#pragma unroll
    for (int kc = 0; kc < 2; ++kc) {
        int h = 2*kc + q2;
        uint4 v = (q2 == 0) ? make_uint4(d0[h], d1[h], p0[h], p1[h])
                            : make_uint4(p0[h], p1[h], d0[h], d1[h]);
        out[tile_ofs_u4 + (size_t)kc * 64 + l] = v;
    }
}

// R3 task map: nc=1 (T<12), 2 (12..23), 3 (24..31).
// Op slots (chunks cc>=1): T 12..23 -> 1 slot, 24..31 -> 2. 28/batch.
__device__ __forceinline__ int obase(int T) {
    return (T < 24) ? (T - 12) : 12 + (T - 24) * 2;
}
// Dp slots (all chunks of split tasks): 48/batch.
__device__ __forceinline__ int dbase(int T) {
    return (T < 24) ? (T - 12) * 2 : 24 + (T - 24) * 3;
}

// ---------------------------------------------------------------------------
// Fused projection. grid (64 s-tiles, 4 batch, 3): z=0 Q, z=1 K, z=2 V (all
// 4 e-chunks; Xv staged once).  (Unchanged from R12.)
// ---------------------------------------------------------------------------
__global__ __launch_bounds__(256) void proj(const float* __restrict__ Xq,
                                            const float* __restrict__ Xk,
                                            const float* __restrict__ Xv,
                                            const float* __restrict__ Wq,
                                            const float* __restrict__ Wk,
                                            const float* __restrict__ Wv,
                                            uint4* __restrict__ qf,
                                            uint4* __restrict__ kf,
                                            uint4* __restrict__ vf) {
    __shared__ unsigned short Xs[64][264];
    __shared__ unsigned short Ws[64][264];

    const int z = blockIdx.z;
    const int bx = blockIdx.x, b = blockIdx.y;
    const float* X = (z == 0) ? Xq : (z == 1) ? Xk : Xv;
    const float* W = (z == 0) ? Wq : (z == 1) ? Wk : Wv;
    const int s0 = bx * 64;
    const int tid = threadIdx.x, w = tid >> 6, l = tid & 63, ln = l & 31, q2 = l >> 5;

#pragma unroll
    for (int i = 0; i < 16; ++i) {
        int f = i * 256 + tid;
        int r = f >> 6, c4 = f & 63;
        float4 xv = *(const float4*)&X[((size_t)b * SEQ + s0 + r) * DM + c4 * 4];
        ushort4 h; h.x = f2bf(xv.x); h.y = f2bf(xv.y); h.z = f2bf(xv.z); h.w = f2bf(xv.w);
        *(ushort4*)&Xs[r][c4 * 4] = h;
    }

    if (z < 2) {
#pragma unroll
        for (int i = 0; i < 16; ++i) {
            int f = i * 256 + tid;
            int r = f >> 6, c4 = f & 63;
            float4 wv = *(const float4*)&W[(size_t)r * DM + c4 * 4];
            ushort4 h; h.x = f2bf(wv.x); h.y = f2bf(wv.y); h.z = f2bf(wv.z); h.w = f2bf(wv.w);
            *(ushort4*)&Ws[r][c4 * 4] = h;
        }
        __syncthreads();
        const int msub = w >> 1, nsub = w & 1;
        f32x16 a0 = {}, a1 = {};
#pragma unroll
        for (int c = 0; c < 16; c += 2) {
            bf16x8 af0 = u4bf(*(const uint4*)&Ws[msub*32 + ln][c*16 + q2*8]);
            bf16x8 bf0 = u4bf(*(const uint4*)&Xs[nsub*32 + ln][c*16 + q2*8]);
            a0 = __builtin_amdgcn_mfma_f32_32x32x16_bf16(af0, bf0, a0, 0, 0, 0);
            bf16x8 af1 = u4bf(*(const uint4*)&Ws[msub*32 + ln][(c+1)*16 + q2*8]);
            bf16x8 bf1 = u4bf(*(const uint4*)&Xs[nsub*32 + ln][(c+1)*16 + q2*8]);
            a1 = __builtin_amdgcn_mfma_f32_32x32x16_bf16(af1, bf1, a1, 0, 0, 0);
        }
        f32x16 acc = a0 + a1;
        size_t base = (((size_t)(b*128 + bx*2 + nsub)) * 4 + 2*msub) * 64;
        repack_store(acc, q2, l, (z == 0) ? qf : kf, base);
    } else {
        const int msub = w & 1, nsub = w >> 1;
        for (int ec = 0; ec < 4; ++ec) {
            __syncthreads();
#pragma unroll
            for (int i = 0; i < 16; ++i) {
                int f = i * 256 + tid;
                int r = f >> 6, c4 = f & 63;
                float4 wv = *(const float4*)&W[(size_t)(ec*64 + r) * DM + c4 * 4];
                ushort4 h; h.x = f2bf(wv.x); h.y = f2bf(wv.y); h.z = f2bf(wv.z); h.w = f2bf(wv.w);
                *(ushort4*)&Ws[r][c4 * 4] = h;
            }
            __syncthreads();
            f32x16 a0 = {}, a1 = {};
#pragma unroll
            for (int c = 0; c < 16; c += 2) {
                bf16x8 af0 = u4bf(*(const uint4*)&Xs[msub*32 + ln][c*16 + q2*8]);
                bf16x8 bf0 = u4bf(*(const uint4*)&Ws[nsub*32 + ln][c*16 + q2*8]);
                a0 = __builtin_amdgcn_mfma_f32_32x32x16_bf16(af0, bf0, a0, 0, 0, 0);
                bf16x8 af1 = u4bf(*(const uint4*)&Xs[msub*32 + ln][(c+1)*16 + q2*8]);
                bf16x8 bf1 = u4bf(*(const uint4*)&Ws[nsub*32 + ln][(c+1)*16 + q2*8]);
                a1 = __builtin_amdgcn_mfma_f32_32x32x16_bf16(af1, bf1, a1, 0, 0, 0);
            }
            f32x16 acc = a0 + a1;
            int et = ec*2 + nsub;
            size_t base = (((size_t)(b*8 + et)) * 256 + (size_t)bx*4 + msub*2) * 64;
            repack_store(acc, q2, l, vf, base);
        }
    }
}

// ---------------------------------------------------------------------------
// Attention. 480 blocks x 512 thr, 2 blocks/CU (LDS 34.5KB, ~72 VGPR).
// Block = (b, qh, task): slot = bid&7 -> b = slot>>1, qh = slot&1 (XCD pin).
// task = bid>>3. Block covers 64 q-rows x K-chunk [j0,j1).
// Wave w: S^T (ks=w&3, qg=w>>2): 4 MFMA -> 16 exp -> pack Pb[jt&1][qg][..];
// PV (et=w): oa[2 qsub] += P*V. vbs[kc] refilled for jt+1 immediately after
// its PV use (cross-cell prefetch, ~1500cyc in flight); kaf prefetched
// across the barrier. One barrier/iter (Pb double-buffered).
// ---------------------------------------------------------------------------
__global__ __launch_bounds__(512, 2) void attn(const uint4* __restrict__ qf,
                                               const uint4* __restrict__ kf,
                                               const uint4* __restrict__ vf,
                                               float* __restrict__ out,
                                               unsigned short* __restrict__ Op,
                                               float* __restrict__ Dp) {
    __shared__ uint4 Pb[2][2][8][64];        // 32KB, double-buffered P (64 rows)
    __shared__ float denp[4][2][64];         // [ks][qg][lane]
    __shared__ float dfin[64];

    const int bid = blockIdx.x;
    const int slot = bid & 7;
    const int b = slot >> 1, qh = slot & 1;
    const int task = bid >> 3;               // [0,60)
    int T, cc, nc;
    if (task < 12)      { T = task;                cc = 0;               nc = 1; }
    else if (task < 36) { int q = task - 12; T = 12 + (q >> 1); cc = q & 1;       nc = 2; }
    else                { int q = task - 36; T = 24 + q / 3;    cc = q - 3*(q/3); nc = 3; }
    const int n = T + 1;
    const int j0 = cc * n / nc, j1 = (cc + 1) * n / nc;

    const int tid = threadIdx.x, w = tid >> 6, l = tid & 63, ln = l & 31, q2 = l >> 5;
    const int ks = w & 3, qg = w >> 2;       // S^T role
    const int qsub = qh * 2 + qg;            // global q-sub within T-tile
    const int et = w;                        // PV role: e-tile
    const float cfac = 0.18033688011112042f; // log2(e)/sqrt(64)

    bf16x8 qv[4];
#pragma unroll
    for (int c = 0; c < 4; ++c)
        qv[c] = u4bf(qf[(((size_t)b*128 + T*4 + qsub) * 4 + c) * 64 + l]);

    f32x16 oa[2] = {};
    float den = 0.f;

    uint4 kaf[4];
#pragma unroll
    for (int c = 0; c < 4; ++c)
        kaf[c] = kf[(((size_t)b*128 + j0*4 + ks) * 4 + c) * 64 + l];

    // initial V fill for tile j0 (latency covered by first S^T/exp)
    const size_t vbase = ((size_t)b*8 + et) * 256;
    uint4 vbs[8];
#pragma unroll
    for (int kc = 0; kc < 8; ++kc)
        vbs[kc] = vf[(vbase + (size_t)j0*8 + kc) * 64 + l];

    for (int jt = j0; jt < j1; ++jt) {
        const int buf = jt & 1;
        const bool diag = (jt == T);
        const int jn = (jt + 1 < j1) ? jt + 1 : jt;  // clamped next tile

        // ---- S^T (one q-sub per wave) ----
        f32x16 s = {};
#pragma unroll
        for (int c = 0; c < 4; ++c)
            s = __builtin_amdgcn_mfma_f32_32x32x16_bf16(u4bf(kaf[c]), qv[c], s, 0, 0, 0);

        // ---- exp + mask + den + pack P -> LDS ----
        float pv[16], pd = 0.f;
#pragma unroll
        for (int r = 0; r < 16; ++r) {
            float e = __builtin_exp2f(s[r] * cfac);
            if (diag) {
                int klocal = 4*q2 + (r & 3) + 8*(r >> 2);
                if (ks*32 + klocal > qsub*32 + ln) e = 0.f;
            }
            pv[r] = e; pd += e;
        }
        den += pd;
#pragma unroll
        for (int quad = 0; quad < 4; ++quad) {
            unsigned int lo = pk2bf(pv[4*quad + 0], pv[4*quad + 1]);
            unsigned int hi = pk2bf(pv[4*quad + 2], pv[4*quad + 3]);
            int kcg = ks*2 + (quad >> 1);
            int h   = quad & 1;
            char* dst = (char*)&Pb[buf][qg][kcg][h*32 + ln] + q2*8;
            *(uint2*)dst = make_uint2(lo, hi);
        }
        __syncthreads();
        // ---- prefetch next K-frags (covered by PV) ----
        if (jt + 1 < j1) {
#pragma unroll
            for (int c = 0; c < 4; ++c)
                kaf[c] = kf[(((size_t)b*128 + (jt+1)*4 + ks) * 4 + c) * 64 + l];
        }
        // ---- PV with use-then-refill: vbs[kc] -> tile jn after last use ----
#pragma unroll
        for (int kc = 0; kc < 8; ++kc) {
            bf16x8 vb = u4bf(vbs[kc]);
            vbs[kc] = vf[(vbase + (size_t)jn*8 + kc) * 64 + l];
#pragma unroll
            for (int qsl = 0; qsl < 2; ++qsl) {
                bf16x8 pa = u4bf(Pb[buf][qsl][kc][l]);
                oa[qsl] = __builtin_amdgcn_mfma_f32_32x32x16_bf16(pa, vb, oa[qsl], 0, 0, 0);
            }
        }
    }

    // ---- den reduction across ks-waves/halves (order matches R8 bitwise) ----
    denp[ks][qg][l] = den;
    __syncthreads();
    if (tid < 64) {
        int qgl = tid >> 5, qln = tid & 31;
        float sden = 0.f;
#pragma unroll
        for (int p = 0; p < 4; ++p)
#pragma unroll
            for (int hh = 0; hh < 2; ++hh)
                sden += denp[p][qgl][hh*32 + qln];
        dfin[tid] = (nc == 1) ? 1.0f / sden : sden;
    }
    __syncthreads();

    if (nc == 1) {
#pragma unroll
        for (int qsl = 0; qsl < 2; ++qsl)
#pragma unroll
            for (int r = 0; r < 16; ++r) {
                int qrow = qsl*32 + (r & 3) + 8*(r >> 2) + 4*q2;
                out[((size_t)b*SEQ + T*128 + qh*64 + qrow) * DM + et*32 + ln] = oa[qsl][r] * dfin[qrow];
            }
    } else if (cc == 0) {
        // chunk 0: unnormalized fp32 straight into out (combine divides later)
#pragma unroll
        for (int qsl = 0; qsl < 2; ++qsl)
#pragma unroll
            for (int r = 0; r < 16; ++r) {
                int qrow = qsl*32 + (r & 3) + 8*(r >> 2) + 4*q2;
                out[((size_t)b*SEQ + T*128 + qh*64 + qrow) * DM + et*32 + ln] = oa[qsl][r];
            }
        if (tid < 64) Dp[((size_t)b*48 + dbase(T)) * 128 + qh*64 + tid] = dfin[tid];
    } else {
        size_t pidx = (size_t)b*28 + obase(T) + (cc - 1);
#pragma unroll
        for (int qsl = 0; qsl < 2; ++qsl)
#pragma unroll
            for (int r = 0; r < 16; ++r) {
                int qrow = qsl*32 + (r & 3) + 8*(r >> 2) + 4*q2;
                Op[(pidx*128 + qh*64 + qrow) * DM + et*32 + ln] = f2bf(oa[qsl][r]);
            }
        if (tid < 64) Dp[((size_t)b*48 + dbase(T) + cc) * 128 + qh*64 + tid] = dfin[tid];
    }
}

// ---------------------------------------------------------------------------
// Combine partials for T in [12,32). grid (20, 4, 4 q-quarters) x 256 thr.
// out holds chunk-0's unnormalized fp32; add bf16 chunks >=1, divide by den.
// (Unchanged.)
// ---------------------------------------------------------------------------
__global__ __launch_bounds__(256) void combine(const unsigned short* __restrict__ Op,
                                               const float* __restrict__ Dp,
                                               float* __restrict__ out) {
    const int T = 12 + blockIdx.x, b = blockIdx.y, qq = blockIdx.z;
    const int nc = (T < 24) ? 2 : 3;
    const int t = threadIdx.x;
    const size_t db = (size_t)b*48 + dbase(T);
    const size_t pb = (size_t)b*28 + obase(T);
#pragma unroll 4
    for (int r = 0; r < 32; ++r) {
        int q = qq*32 + r;
        size_t oofs = ((size_t)b*SEQ + T*128 + q) * DM + t;
        float sum = out[oofs];
        float dsum = 0.f;
        for (int c = 0; c < nc; ++c) dsum += Dp[(db + c)*128 + q];
        for (int c = 1; c < nc; ++c) {
            unsigned int uv = Op[((pb + c - 1)*128 + q) * DM + t];
            sum += __builtin_bit_cast(float, uv << 16);
        }
        out[oofs] = sum / dsum;
    }
}

// ---------------------------------------------------------------------------
extern "C" void kernel_launch(void* const* d_in, const int* in_sizes, int n_in,
                              void* d_out, int out_size, void* d_ws, size_t ws_size,
                              hipStream_t stream) {
    const float* enc_q = (const float*)d_in[0];
    const float* enc_k = (const float*)d_in[1];
    const float* enc_v = (const float*)d_in[2];
    // d_in[3] = mask (deterministic causal triu) — not needed
    const float* Wq = (const float*)d_in[4];
    const float* Wk = (const float*)d_in[5];
    const float* Wv = (const float*)d_in[6];
    float* out = (float*)d_out;

    uint4* qf = (uint4*)d_ws;                              // 2MB
    uint4* kf = qf + 131072;                               // 2MB
    uint4* vf = kf + 131072;                               // 8MB
    unsigned short* Op = (unsigned short*)(vf + 524288);   // [4][28][128][256] bf16, 7.34MB
    float* Dp = (float*)(Op + (size_t)4*28*128*256);       // [4][48][128] f32, 98KB

    proj<<<dim3(64, 4, 3), 256, 0, stream>>>(enc_q, enc_k, enc_v, Wq, Wk, Wv, qf, kf, vf);
    attn<<<480, 512, 0, stream>>>(qf, kf, vf, out, Op, Dp);
    combine<<<dim3(20, 4, 4), 256, 0, stream>>>(Op, Dp, out);
}